// Round 8
// baseline (8880.378 us; speedup 1.0000x reference)
//
#include <hip/hip_runtime.h>

#define BATCH  4096
#define TIN    256
#define NIN    4
#define HDIM   64
#define TOUT   180
#define BB     16      // batch elements per block
#define NTHR   576     // 3 groups x 192 rows, 9 waves
#define HP     68      // padded stride for h arrays
#define G3     192     // 3*H gate rows
#define PADF   4096    // 16 KB LDS pad (keeps r6's codegen env; 1 block/CU anyway)

__device__ __forceinline__ float sigm(float v){ return 1.0f/(1.0f+__expf(-v)); }
__device__ __forceinline__ float tanh_(float v){ return 2.0f/(1.0f+__expf(-2.0f*v)) - 1.0f; }

// HISTORY (rocprof-driven):
//  r1: persistent 64-VGPR weight row, VGPR budget 84 -> scratch spill, 20.7 GB
//      HBM FETCH/dispatch (= 436 steps x 47 MB scratch set), 12.1 ms.
//  r6: +LDS pad + waves_per_eu: compiler switched spill->remat (global reload
//      inside b-loop); FETCH 38 MB (L2 absorbs weights) but L2-latency
//      serialized: 8.2 ms, VALUBusy 35%, VGPR still 84.
//  NOW: design FOR the 84-reg budget: weights are PHASE-TRANSIENT - batched
//      reload of the full row at phase top (one L2 latency per phase, not per
//      b-iter), dead at the barrier. asm pointer-launder stops LICM from
//      hoisting the loads back across barriers.
__global__ __launch_bounds__(NTHR)
__attribute__((amdgpu_waves_per_eu(1, 2)))
void gru_seq(const float* __restrict__ x,
             const float* __restrict__ eWih0, const float* __restrict__ eWhh0,
             const float* __restrict__ ebih0, const float* __restrict__ ebhh0,
             const float* __restrict__ eWih1, const float* __restrict__ eWhh1,
             const float* __restrict__ ebih1, const float* __restrict__ ebhh1,
             const float* __restrict__ dWih0, const float* __restrict__ dWhh0,
             const float* __restrict__ dbih0, const float* __restrict__ dbhh0,
             const float* __restrict__ dWih1, const float* __restrict__ dWhh1,
             const float* __restrict__ dbih1, const float* __restrict__ dbhh1,
             const float* __restrict__ Won,  const float* __restrict__ bon,
             const float* __restrict__ Wcv,  const float* __restrict__ bcv,
             float* __restrict__ out)
{
  __shared__ float h1[BB][HP];     // layer-0 hidden (encoder) == d1 (decoder)
  __shared__ float h2[BB][HP];     // layer-1 hidden == d2
  __shared__ float gi[BB][G3];     // input-side gates (reused L0 then L1)
  __shared__ float g0[BB][G3];     // hidden-side gates, layer 0
  __shared__ float g1[BB][G3];     // hidden-side gates, layer 1
  __shared__ float xb[2][BB][NIN]; // double-buffered x tile
  __shared__ float pv[BB];         // decoder feedback (cv)
  __shared__ float hw[2][HDIM];    // head weights (Won, Wcv)
  __shared__ float hbb[2];         // head biases
  __shared__ float lds_pad[PADF];  // occupancy/codegen pad (see header)

  const int tid = threadIdx.x;
  const int m   = tid / G3;        // 0: Whh0(+Wih0)  1: Wih1  2: Whh1
  const int j   = tid - m*G3;      // gate row 0..191
  const int bbase = blockIdx.x * BB;

  { volatile float* vp = lds_pad; vp[tid] = 0.f; }

  // persistent scalars only (cheap): biases + Wih0 row (4 floats)
  float4 wi0 = make_float4(0.f,0.f,0.f,0.f);
  float bi = 0.f, bh = 0.f;
  if (m==0){ wi0 = *(const float4*)(eWih0 + j*NIN); bi = ebih0[j]; bh = ebhh0[j]; }
  else if (m==1){ bi = ebih1[j]; }
  else          { bh = ebhh1[j]; }

  // per-thread weight-row base (encoder): reloaded transiently each phase
  const float4* Wre = (const float4*)(((m==0)? eWhh0 : (m==1)? eWih1 : eWhh1) + j*HDIM);

  // init state + first x tile
  for (int u=tid; u<BB*HP; u+=NTHR){ (&h1[0][0])[u]=0.f; (&h2[0][0])[u]=0.f; }
  if (tid < BB)
    *(float4*)&xb[0][tid][0] = *(const float4*)(x + (size_t)(bbase+tid)*TIN*NIN);
  __syncthreads();

  // transient row load: launder pointer so LICM cannot hoist the 16 loads out
  // of the t-loop (which would recreate the cross-barrier 64-reg live range)
#define LOAD_ROW(W, P)                            \
  { const float4* p_ = (P);                       \
    asm volatile("" : "+v"(p_));                  \
    _Pragma("unroll")                             \
    for (int kk=0;kk<16;kk++) (W)[kk] = p_[kk]; }

#define DOT_ROW(W, HV, A0,A1,A2,A3)               \
    float A0=0.f,A1=0.f,A2=0.f,A3=0.f;            \
    _Pragma("unroll")                             \
    for (int kk=0;kk<16;kk++){ float4 h4 = (HV)[kk]; \
      A0 += (W)[kk].x*h4.x; A1 += (W)[kk].y*h4.y;    \
      A2 += (W)[kk].z*h4.z; A3 += (W)[kk].w*h4.w; }

  // ================= encoder: 256 steps =================
  for (int t=0;t<TIN;t++){
    const int cur = t & 1;
    if (m==0){
      float4 w[16]; LOAD_ROW(w, Wre);
      for (int b=0;b<BB;b++){
        float ai = bi + wi0.x*xb[cur][b][0] + wi0.y*xb[cur][b][1]
                      + wi0.z*xb[cur][b][2] + wi0.w*xb[cur][b][3];
        const float4* hv = (const float4*)&h1[b][0];
        DOT_ROW(w, hv, a0,a1,a2,a3);
        gi[b][j] = ai;
        g0[b][j] = bh + ((a0+a1)+(a2+a3));
      }
    } else if (m==2){
      float4 w[16]; LOAD_ROW(w, Wre);
      for (int b=0;b<BB;b++){
        const float4* hv = (const float4*)&h2[b][0];
        DOT_ROW(w, hv, a0,a1,a2,a3);
        g1[b][j] = bh + ((a0+a1)+(a2+a3));
      }
    } else {
      const int l = tid - G3;
      if (l < BB && t+1 < TIN)
        *(float4*)&xb[cur^1][l][0] =
          *(const float4*)(x + ((size_t)(bbase+l)*TIN + (t+1))*NIN);
    }
    __syncthreads();
    // Phase B: combine layer 0 -> h1
    for (int u=tid; u<BB*HDIM; u+=NTHR){
      const int b=u>>6, q=u&63;
      const float r = sigm(gi[b][q]      + g0[b][q]);
      const float z = sigm(gi[b][64+q]   + g0[b][64+q]);
      const float n = tanh_(gi[b][128+q] + r*g0[b][128+q]);
      h1[b][q] = (1.f-z)*n + z*h1[b][q];
    }
    __syncthreads();
    // Phase C: m1 -> gi1 = Wih1 @ h1_new
    if (m==1){
      float4 w[16]; LOAD_ROW(w, Wre);
      for (int b=0;b<BB;b++){
        const float4* hv = (const float4*)&h1[b][0];
        DOT_ROW(w, hv, a0,a1,a2,a3);
        gi[b][j] = bi + ((a0+a1)+(a2+a3));
      }
    }
    __syncthreads();
    // Phase D: combine layer 1 -> h2
    for (int u=tid; u<BB*HDIM; u+=NTHR){
      const int b=u>>6, q=u&63;
      const float r = sigm(gi[b][q]      + g1[b][q]);
      const float z = sigm(gi[b][64+q]   + g1[b][64+q]);
      const float n = tanh_(gi[b][128+q] + r*g1[b][128+q]);
      h2[b][q] = (1.f-z)*n + z*h2[b][q];
    }
    __syncthreads();
  }

  // ================= switch to decoder weights =================
  const float4* Wrd = (const float4*)(((m==0)? dWhh0 : (m==1)? dWih1 : dWhh1) + j*HDIM);
  float wi0d = 0.f;
  if (m==0){ wi0d = dWih0[j]; bi = dbih0[j]; bh = dbhh0[j]; }
  else if (m==1){ bi = dbih1[j]; }
  else          { bh = dbhh1[j]; }
  if (tid < HDIM){ hw[0][tid] = Won[tid]; hw[1][tid] = Wcv[tid]; }
  if (tid == 0){ hbb[0] = bon[0]; hbb[1] = bcv[0]; }
  if (tid < BB) pv[tid] = 0.f;
  __syncthreads();

  // ================= decoder: 180 steps =================
  for (int s=0;s<TOUT;s++){
    if (m==0){
      float4 w[16]; LOAD_ROW(w, Wrd);
      for (int b=0;b<BB;b++){
        const float4* hv = (const float4*)&h1[b][0];
        DOT_ROW(w, hv, a0,a1,a2,a3);
        gi[b][j] = bi + wi0d*pv[b];
        g0[b][j] = bh + ((a0+a1)+(a2+a3));
      }
    } else if (m==2){
      float4 w[16]; LOAD_ROW(w, Wrd);
      for (int b=0;b<BB;b++){
        const float4* hv = (const float4*)&h2[b][0];
        DOT_ROW(w, hv, a0,a1,a2,a3);
        g1[b][j] = bh + ((a0+a1)+(a2+a3));
      }
    }
    __syncthreads();
    for (int u=tid; u<BB*HDIM; u+=NTHR){
      const int b=u>>6, q=u&63;
      const float r = sigm(gi[b][q]      + g0[b][q]);
      const float z = sigm(gi[b][64+q]   + g0[b][64+q]);
      const float n = tanh_(gi[b][128+q] + r*g0[b][128+q]);
      h1[b][q] = (1.f-z)*n + z*h1[b][q];
    }
    __syncthreads();
    if (m==1){
      float4 w[16]; LOAD_ROW(w, Wrd);
      for (int b=0;b<BB;b++){
        const float4* hv = (const float4*)&h1[b][0];
        DOT_ROW(w, hv, a0,a1,a2,a3);
        gi[b][j] = bi + ((a0+a1)+(a2+a3));
      }
    }
    __syncthreads();
    for (int u=tid; u<BB*HDIM; u+=NTHR){
      const int b=u>>6, q=u&63;
      const float r = sigm(gi[b][q]      + g1[b][q]);
      const float z = sigm(gi[b][64+q]   + g1[b][64+q]);
      const float n = tanh_(gi[b][128+q] + r*g1[b][128+q]);
      h2[b][q] = (1.f-z)*n + z*h2[b][q];
    }
    __syncthreads();
    // heads: logit & cv, feed cv back
    if (tid < 32){
      const int hd = tid>>4, b = tid&15;
      float a = hbb[hd];
      const float4* hv = (const float4*)&h2[b][0];
      #pragma unroll
      for (int kk=0;kk<16;kk++){ float4 h4 = hv[kk];
        a += hw[hd][kk*4+0]*h4.x + hw[hd][kk*4+1]*h4.y
           + hw[hd][kk*4+2]*h4.z + hw[hd][kk*4+3]*h4.w; }
      const int bg = bbase + b;
      if (hd==0) out[(size_t)bg*TOUT + s] = a;
      else { out[(size_t)BATCH*TOUT + (size_t)bg*TOUT + s] = a; pv[b] = a; }
    }
    __syncthreads();
  }
}

extern "C" void kernel_launch(void* const* d_in, const int* in_sizes, int n_in,
                              void* d_out, int out_size, void* d_ws, size_t ws_size,
                              hipStream_t stream)
{
  const float* x     = (const float*)d_in[0];
  const float* eWih0 = (const float*)d_in[1];
  const float* eWhh0 = (const float*)d_in[2];
  const float* ebih0 = (const float*)d_in[3];
  const float* ebhh0 = (const float*)d_in[4];
  const float* eWih1 = (const float*)d_in[5];
  const float* eWhh1 = (const float*)d_in[6];
  const float* ebih1 = (const float*)d_in[7];
  const float* ebhh1 = (const float*)d_in[8];
  const float* dWih0 = (const float*)d_in[9];
  const float* dWhh0 = (const float*)d_in[10];
  const float* dbih0 = (const float*)d_in[11];
  const float* dbhh0 = (const float*)d_in[12];
  const float* dWih1 = (const float*)d_in[13];
  const float* dWhh1 = (const float*)d_in[14];
  const float* dbih1 = (const float*)d_in[15];
  const float* dbhh1 = (const float*)d_in[16];
  const float* Won   = (const float*)d_in[17];
  const float* bon   = (const float*)d_in[18];
  const float* Wcv   = (const float*)d_in[19];
  const float* bcv   = (const float*)d_in[20];

  gru_seq<<<BATCH/BB, NTHR, 0, stream>>>(
      x, eWih0, eWhh0, ebih0, ebhh0, eWih1, eWhh1, ebih1, ebhh1,
      dWih0, dWhh0, dbih0, dbhh0, dWih1, dWhh1, dbih1, dbhh1,
      Won, bon, Wcv, bcv, (float*)d_out);
}

// Round 9
// 8551.125 us; speedup vs baseline: 1.0385x; 1.0385x over previous
//
#include <hip/hip_runtime.h>

#define BATCH  4096
#define TIN    256
#define NIN    4
#define HDIM   64
#define TOUT   180
#define BB     8       // batch elements per block (grid 512 -> 2 blocks/CU)
#define NTHR   576     // 3 groups x 192 rows, 9 waves
#define HP     68      // padded stride for h arrays
#define G3     192     // 3*H gate rows
#define PADF   6144    // 24 KB pad -> ~55 KB LDS: pins occupancy target at 2 blocks/CU

__device__ __forceinline__ float sigm(float v){ return 1.0f/(1.0f+__expf(-v)); }
__device__ __forceinline__ float tanh_(float v){ return 2.0f/(1.0f+__expf(-2.0f*v)) - 1.0f; }

// HISTORY (rocprof-driven):
//  r1: persistent 64-VGPR w-row @ budget 84 -> scratch spill -> 20.7 GB HBM, 12.1 ms.
//  r6: LDS pad; remat-from-L2 per b-iter; FETCH 38 MB, 8.2 ms, VALUBusy 35.
//  r8: phase-transient w reload (launder): VGPR=84, FETCH 14.7 MB (no spill!) but
//      8.9 ms -> NOT memory: phase serialization (1/3..2/3 threads live) + 4-5
//      barriers/step + unhidden ds_read/L2 latency at 2.25 waves/SIMD.
//  NOW: layer-pipelined supersteps: L1[t] and L2[t-1] matvecs CONCURRENT (all 3
//      groups in one phase), one combine phase for both layers. Encoder 2
//      barriers/superstep, decoder 3 (cv feedback folded into d1-combine as a
//      redundant per-lane dot). BB=8 grid=512 + ~55KB LDS + launch_bounds(,5)
//      -> 2 resident blocks/CU (18 waves) interleave phases/latency.
#define LOAD_ROW(W, P)                            \
  { const float4* p_ = (P);                       \
    asm volatile("" : "+v"(p_));                  \
    _Pragma("unroll")                             \
    for (int kk=0;kk<16;kk++) (W)[kk] = p_[kk]; }

#define DOT_ROW(W, HV, A0,A1,A2,A3)               \
    float A0=0.f,A1=0.f,A2=0.f,A3=0.f;            \
    _Pragma("unroll")                             \
    for (int kk=0;kk<16;kk++){ float4 h4 = (HV)[kk]; \
      A0 += (W)[kk].x*h4.x; A1 += (W)[kk].y*h4.y;    \
      A2 += (W)[kk].z*h4.z; A3 += (W)[kk].w*h4.w; }

__global__ __launch_bounds__(NTHR, 5)   // cap alloc ~512/5=102 regs so 2 blocks fit
void gru_seq(const float* __restrict__ x,
             const float* __restrict__ eWih0, const float* __restrict__ eWhh0,
             const float* __restrict__ ebih0, const float* __restrict__ ebhh0,
             const float* __restrict__ eWih1, const float* __restrict__ eWhh1,
             const float* __restrict__ ebih1, const float* __restrict__ ebhh1,
             const float* __restrict__ dWih0, const float* __restrict__ dWhh0,
             const float* __restrict__ dbih0, const float* __restrict__ dbhh0,
             const float* __restrict__ dWih1, const float* __restrict__ dWhh1,
             const float* __restrict__ dbih1, const float* __restrict__ dbhh1,
             const float* __restrict__ Won,  const float* __restrict__ bon,
             const float* __restrict__ Wcv,  const float* __restrict__ bcv,
             float* __restrict__ out)
{
  __shared__ float h1[BB][HP];       // L1 hidden (enc) == d1 (dec)
  __shared__ float h2[BB][HP];       // L2 hidden == d2
  __shared__ float gi0s[BB][G3];     // input-side gates, layer 0
  __shared__ float gi1s[BB][G3];     // input-side gates, layer 1
  __shared__ float g0s[BB][G3];      // hidden-side gates, layer 0
  __shared__ float g1s[BB][G3];      // hidden-side gates, layer 1
  __shared__ float xb[2][BB][NIN];   // double-buffered x tile
  __shared__ float hw[2][HDIM];      // head weights (Won, Wcv)
  __shared__ float hbb[2];           // head biases
  __shared__ float dwih0[G3];        // decoder Wih0 column (192x1)
  __shared__ float dbih0s[G3];       // decoder bih0
  __shared__ float lds_pad[PADF];    // occupancy pad (see header)

  const int tid = threadIdx.x;
  const int m   = tid / G3;          // 0: Whh0  1: Wih1  2: Whh1
  const int j   = tid - m*G3;        // gate row 0..191
  const int bbase = blockIdx.x * BB;

  { volatile float* vp = lds_pad; vp[tid] = 0.f; }

  // encoder per-thread scalars
  float4 wi0 = make_float4(0.f,0.f,0.f,0.f);
  float bi = 0.f, bh = 0.f;
  if (m==0){ wi0 = *(const float4*)(eWih0 + j*NIN); bi = ebih0[j]; bh = ebhh0[j]; }
  else if (m==1){ bi = ebih1[j]; }
  else          { bh = ebhh1[j]; }
  const float4* Wre = (const float4*)(((m==0)? eWhh0 : (m==1)? eWih1 : eWhh1) + j*HDIM);

  for (int u=tid; u<BB*HP; u+=NTHR){ (&h1[0][0])[u]=0.f; (&h2[0][0])[u]=0.f; }
  if (tid < BB)
    *(float4*)&xb[0][tid][0] = *(const float4*)(x + (size_t)(bbase+tid)*TIN*NIN);
  __syncthreads();

  // ====== encoder: supersteps t=0..TIN; L1 step t (t<TIN) || L2 step t-1 (t>=1)
  for (int t=0;t<=TIN;t++){
    const int cur = t & 1;
    if (m==0){
      if (t < TIN){
        float4 w[16]; LOAD_ROW(w, Wre);
        for (int b=0;b<BB;b++){
          float ai = bi + wi0.x*xb[cur][b][0] + wi0.y*xb[cur][b][1]
                        + wi0.z*xb[cur][b][2] + wi0.w*xb[cur][b][3];
          const float4* hv = (const float4*)&h1[b][0];
          DOT_ROW(w, hv, a0,a1,a2,a3);
          gi0s[b][j] = ai;
          g0s[b][j]  = bh + ((a0+a1)+(a2+a3));
        }
      }
    } else if (m==1){
      if (t >= 1){
        float4 w[16]; LOAD_ROW(w, Wre);
        for (int b=0;b<BB;b++){
          const float4* hv = (const float4*)&h1[b][0];
          DOT_ROW(w, hv, a0,a1,a2,a3);
          gi1s[b][j] = bi + ((a0+a1)+(a2+a3));
        }
      }
    } else {
      if (t >= 1){
        float4 w[16]; LOAD_ROW(w, Wre);
        for (int b=0;b<BB;b++){
          const float4* hv = (const float4*)&h2[b][0];
          DOT_ROW(w, hv, a0,a1,a2,a3);
          g1s[b][j] = bh + ((a0+a1)+(a2+a3));
        }
      }
    }
    __syncthreads();
    // combine both layers in one phase
    for (int u=tid; u<2*BB*HDIM; u+=NTHR){
      if (u < BB*HDIM){
        if (t < TIN){
          const int b=u>>6, q=u&63;
          const float r = sigm(gi0s[b][q]      + g0s[b][q]);
          const float z = sigm(gi0s[b][64+q]   + g0s[b][64+q]);
          const float n = tanh_(gi0s[b][128+q] + r*g0s[b][128+q]);
          h1[b][q] = (1.f-z)*n + z*h1[b][q];
        }
      } else {
        if (t >= 1){
          const int b=(u>>6)-BB, q=u&63;
          const float r = sigm(gi1s[b][q]      + g1s[b][q]);
          const float z = sigm(gi1s[b][64+q]   + g1s[b][64+q]);
          const float n = tanh_(gi1s[b][128+q] + r*g1s[b][128+q]);
          h2[b][q] = (1.f-z)*n + z*h2[b][q];
        }
      }
    }
    if (tid >= 512 && tid < 512+BB && (t+1) < TIN)
      *(float4*)&xb[cur^1][tid-512][0] =
        *(const float4*)(x + ((size_t)(bbase+(tid-512))*TIN + (t+1))*NIN);
    __syncthreads();
  }

  // ====== decoder init: switch weights, stage head + dWih0/dbih0 into LDS
  const float4* Wrd = (const float4*)(((m==0)? dWhh0 : (m==1)? dWih1 : dWhh1) + j*HDIM);
  if (m==0){ bh = dbhh0[j]; }
  else if (m==1){ bi = dbih1[j]; }
  else          { bh = dbhh1[j]; }
  if (tid < HDIM)               hw[0][tid] = Won[tid];
  else if (tid < 2*HDIM)        hw[1][tid-HDIM] = Wcv[tid-HDIM];
  else if (tid < 2*HDIM+G3)     dwih0[tid-2*HDIM] = dWih0[tid-2*HDIM];
  else if (tid < 2*HDIM+2*G3)   dbih0s[tid-2*HDIM-G3] = dbih0[tid-2*HDIM-G3];
  if (tid == 560){ hbb[0] = bon[0]; hbb[1] = bcv[0]; }
  __syncthreads();

  // ====== decoder: supersteps s=0..TOUT; d1 step s (s<TOUT) || d2 step s-1 + heads (s>=1)
  for (int s=0;s<=TOUT;s++){
    if (m==0){
      if (s < TOUT){
        float4 w[16]; LOAD_ROW(w, Wrd);
        for (int b=0;b<BB;b++){
          const float4* hv = (const float4*)&h1[b][0];
          DOT_ROW(w, hv, a0,a1,a2,a3);
          g0s[b][j] = bh + ((a0+a1)+(a2+a3));
        }
      }
    } else if (m==1){
      if (s >= 1){
        float4 w[16]; LOAD_ROW(w, Wrd);
        for (int b=0;b<BB;b++){
          const float4* hv = (const float4*)&h1[b][0];
          DOT_ROW(w, hv, a0,a1,a2,a3);
          gi1s[b][j] = bi + ((a0+a1)+(a2+a3));
        }
      }
    } else {
      if (s >= 1){
        float4 w[16]; LOAD_ROW(w, Wrd);
        for (int b=0;b<BB;b++){
          const float4* hv = (const float4*)&h2[b][0];
          DOT_ROW(w, hv, a0,a1,a2,a3);
          g1s[b][j] = bh + ((a0+a1)+(a2+a3));
        }
      }
    }
    __syncthreads();
    // combine d2[s-1]
    if (s >= 1){
      for (int u=tid; u<BB*HDIM; u+=NTHR){
        const int b=u>>6, q=u&63;
        const float r = sigm(gi1s[b][q]      + g1s[b][q]);
        const float z = sigm(gi1s[b][64+q]   + g1s[b][64+q]);
        const float n = tanh_(gi1s[b][128+q] + r*g1s[b][128+q]);
        h2[b][q] = (1.f-z)*n + z*h2[b][q];
      }
    }
    __syncthreads();
    // heads (s>=1) + combine d1[s] (s<TOUT); cv computed redundantly per lane
    for (int u=tid; u<BB*HDIM; u+=NTHR){
      const int b=u>>6, q=u&63;
      float cv = 0.f;
      if (s >= 1){
        const float4* hv = (const float4*)&h2[b][0];
        const float4* wv = (const float4*)&hw[1][0];
        float a = hbb[1];
        #pragma unroll
        for (int kk=0;kk<16;kk++){ float4 h4 = hv[kk]; float4 w4 = wv[kk];
          a += w4.x*h4.x + w4.y*h4.y + w4.z*h4.z + w4.w*h4.w; }
        cv = a;
        if (q==0) out[(size_t)BATCH*TOUT + (size_t)(bbase+b)*TOUT + (s-1)] = cv;
        if (q==1){
          const float4* wv0 = (const float4*)&hw[0][0];
          float al = hbb[0];
          #pragma unroll
          for (int kk=0;kk<16;kk++){ float4 h4 = hv[kk]; float4 w4 = wv0[kk];
            al += w4.x*h4.x + w4.y*h4.y + w4.z*h4.z + w4.w*h4.w; }
          out[(size_t)(bbase+b)*TOUT + (s-1)] = al;
        }
      }
      if (s < TOUT){
        const float r = sigm((dbih0s[q]      + dwih0[q]*cv)      + g0s[b][q]);
        const float z = sigm((dbih0s[64+q]   + dwih0[64+q]*cv)   + g0s[b][64+q]);
        const float n = tanh_((dbih0s[128+q] + dwih0[128+q]*cv)  + r*g0s[b][128+q]);
        h1[b][q] = (1.f-z)*n + z*h1[b][q];
      }
    }
    __syncthreads();
  }
}

extern "C" void kernel_launch(void* const* d_in, const int* in_sizes, int n_in,
                              void* d_out, int out_size, void* d_ws, size_t ws_size,
                              hipStream_t stream)
{
  const float* x     = (const float*)d_in[0];
  const float* eWih0 = (const float*)d_in[1];
  const float* eWhh0 = (const float*)d_in[2];
  const float* ebih0 = (const float*)d_in[3];
  const float* ebhh0 = (const float*)d_in[4];
  const float* eWih1 = (const float*)d_in[5];
  const float* eWhh1 = (const float*)d_in[6];
  const float* ebih1 = (const float*)d_in[7];
  const float* ebhh1 = (const float*)d_in[8];
  const float* dWih0 = (const float*)d_in[9];
  const float* dWhh0 = (const float*)d_in[10];
  const float* dbih0 = (const float*)d_in[11];
  const float* dbhh0 = (const float*)d_in[12];
  const float* dWih1 = (const float*)d_in[13];
  const float* dWhh1 = (const float*)d_in[14];
  const float* dbih1 = (const float*)d_in[15];
  const float* dbhh1 = (const float*)d_in[16];
  const float* Won   = (const float*)d_in[17];
  const float* bon   = (const float*)d_in[18];
  const float* Wcv   = (const float*)d_in[19];
  const float* bcv   = (const float*)d_in[20];

  gru_seq<<<BATCH/BB, NTHR, 0, stream>>>(
      x, eWih0, eWhh0, ebih0, ebhh0, eWih1, eWhh1, ebih1, ebhh1,
      dWih0, dWhh0, dbih0, dbhh0, dWih1, dWhh1, dbih1, dbhh1,
      Won, bon, Wcv, bcv, (float*)d_out);
}

// Round 12
// 5553.593 us; speedup vs baseline: 1.5990x; 1.5397x over previous
//
#include <hip/hip_runtime.h>

#define BATCH  4096
#define TIN    256
#define NIN    4
#define HDIM   64
#define TOUT   180
#define BB     16      // batch elements per block; grid 256 = 1 block/CU
#define NTHR   576     // 3 groups x 192 rows, 9 waves
#define HP     68      // padded stride for h arrays (272 B, float4-aligned)
#define G3     192     // 3*H gate rows

__device__ __forceinline__ float sigm(float v){ return 1.0f/(1.0f+__expf(-v)); }
__device__ __forceinline__ float tanh_(float v){ return 2.0f/(1.0f+__expf(-2.0f*v)) - 1.0f; }

// HISTORY (rocprof-driven):
//  r1: persistent 64-VGPR w-row @ budget 84 -> scratch spill -> 20.7 GB HBM, 12.1 ms.
//  r6: LDS pad: remat-from-L2 per b-iter; 8.2 ms, VALUBusy 35, VGPR 84.
//  r8: phase-transient 16xfloat4 reload: no spill (FETCH 14.7 MB) but 8.9 ms.
//  r9: superstep pipelining (correct, kept) + launch_bounds(,5): allocator gave
//      VGPR=48 and spilled w wholesale -> WRITE_SIZE 2.36 GB of scratch stores.
//  LESSON: >=64 live weight floats per thread ALWAYS get spilled. Design to
//      ~65-reg peak: two 8xfloat4 half-row passes + BB scalar accumulators,
//      sched_barrier(0) between halves so their loads don't co-schedule.
//      Plain launch_bounds (default 84 budget), no pad, no waves_per_eu.

template<int HALF>
__device__ __forceinline__ void matvec_half(const float4* Wr,
                                            const float (*H)[HP],
                                            float* acc){
  const float4* p_ = Wr + HALF*8;
  asm volatile("" : "+v"(p_));       // launder: keep loads inside the t-loop
  float4 w[8];
  #pragma unroll
  for (int kk=0;kk<8;kk++) w[kk] = p_[kk];
  #pragma unroll
  for (int b=0;b<BB;b++){
    const float4* hv = (const float4*)(&H[b][0]) + HALF*8;  // uniform -> LDS broadcast
    float s0=0.f,s1=0.f,s2=0.f,s3=0.f;
    #pragma unroll
    for (int kk=0;kk<8;kk++){ float4 h4 = hv[kk];
      s0 += w[kk].x*h4.x; s1 += w[kk].y*h4.y;
      s2 += w[kk].z*h4.z; s3 += w[kk].w*h4.w; }
    acc[b] += (s0+s1)+(s2+s3);
  }
}

__global__ __launch_bounds__(NTHR)
void gru_seq(const float* __restrict__ x,
             const float* __restrict__ eWih0, const float* __restrict__ eWhh0,
             const float* __restrict__ ebih0, const float* __restrict__ ebhh0,
             const float* __restrict__ eWih1, const float* __restrict__ eWhh1,
             const float* __restrict__ ebih1, const float* __restrict__ ebhh1,
             const float* __restrict__ dWih0, const float* __restrict__ dWhh0,
             const float* __restrict__ dbih0, const float* __restrict__ dbhh0,
             const float* __restrict__ dWih1, const float* __restrict__ dWhh1,
             const float* __restrict__ dbih1, const float* __restrict__ dbhh1,
             const float* __restrict__ Won,  const float* __restrict__ bon,
             const float* __restrict__ Wcv,  const float* __restrict__ bcv,
             float* __restrict__ out)
{
  __shared__ float h1[BB][HP];       // L1 hidden (enc) == d1 (dec)
  __shared__ float h2[BB][HP];       // L2 hidden == d2
  __shared__ float gi0s[BB][G3];     // input-side gates, layer 0
  __shared__ float gi1s[BB][G3];     // input-side gates, layer 1
  __shared__ float g0s[BB][G3];      // hidden-side gates, layer 0
  __shared__ float g1s[BB][G3];      // hidden-side gates, layer 1
  __shared__ float xb[2][BB][NIN];   // double-buffered x tile
  __shared__ float hw[2][HDIM];      // head weights (Won, Wcv)
  __shared__ float hbb[2];           // head biases
  __shared__ float dwih0[G3];        // decoder Wih0 column (192x1)
  __shared__ float dbih0s[G3];       // decoder bih0

  const int tid = threadIdx.x;
  const int m   = tid / G3;          // 0: Whh0  1: Wih1  2: Whh1
  const int j   = tid - m*G3;        // gate row 0..191
  const int bbase = blockIdx.x * BB;

  // persistent scalars (cheap): biases + Wih0 row (4 floats)
  float4 wi0 = make_float4(0.f,0.f,0.f,0.f);
  float bi = 0.f, bh = 0.f;
  if (m==0){ wi0 = *(const float4*)(eWih0 + j*NIN); bi = ebih0[j]; bh = ebhh0[j]; }
  else if (m==1){ bi = ebih1[j]; }
  else          { bh = ebhh1[j]; }
  const float4* Wre = (const float4*)(((m==0)? eWhh0 : (m==1)? eWih1 : eWhh1) + j*HDIM);

  for (int u=tid; u<BB*HP; u+=NTHR){ (&h1[0][0])[u]=0.f; (&h2[0][0])[u]=0.f; }
  if (tid < BB)
    *(float4*)&xb[0][tid][0] = *(const float4*)(x + (size_t)(bbase+tid)*TIN*NIN);
  __syncthreads();

  // ====== encoder: supersteps; L1 step t (t<TIN) || L2 step t-1 (t>=1)
  for (int t=0;t<=TIN;t++){
    const int cur = t & 1;
    if (m==0){
      if (t < TIN){
        float acc[BB];
        #pragma unroll
        for (int b=0;b<BB;b++) acc[b]=0.f;
        matvec_half<0>(Wre, h1, acc);
        __builtin_amdgcn_sched_barrier(0);
        matvec_half<1>(Wre, h1, acc);
        #pragma unroll
        for (int b=0;b<BB;b++){
          float4 xv = *(const float4*)&xb[cur][b][0];
          gi0s[b][j] = bi + wi0.x*xv.x + wi0.y*xv.y + wi0.z*xv.z + wi0.w*xv.w;
          g0s[b][j]  = bh + acc[b];
        }
      }
    } else if (m==1){
      if (t >= 1){
        float acc[BB];
        #pragma unroll
        for (int b=0;b<BB;b++) acc[b]=0.f;
        matvec_half<0>(Wre, h1, acc);
        __builtin_amdgcn_sched_barrier(0);
        matvec_half<1>(Wre, h1, acc);
        #pragma unroll
        for (int b=0;b<BB;b++) gi1s[b][j] = bi + acc[b];
      }
    } else {
      if (t >= 1){
        float acc[BB];
        #pragma unroll
        for (int b=0;b<BB;b++) acc[b]=0.f;
        matvec_half<0>(Wre, h2, acc);
        __builtin_amdgcn_sched_barrier(0);
        matvec_half<1>(Wre, h2, acc);
        #pragma unroll
        for (int b=0;b<BB;b++) g1s[b][j] = bh + acc[b];
      }
    }
    __syncthreads();
    // combine both layers in one phase
    for (int u=tid; u<2*BB*HDIM; u+=NTHR){
      if (u < BB*HDIM){
        if (t < TIN){
          const int b=u>>6, q=u&63;
          const float r = sigm(gi0s[b][q]      + g0s[b][q]);
          const float z = sigm(gi0s[b][64+q]   + g0s[b][64+q]);
          const float n = tanh_(gi0s[b][128+q] + r*g0s[b][128+q]);
          h1[b][q] = (1.f-z)*n + z*h1[b][q];
        }
      } else {
        if (t >= 1){
          const int b=(u>>6)-BB, q=u&63;
          const float r = sigm(gi1s[b][q]      + g1s[b][q]);
          const float z = sigm(gi1s[b][64+q]   + g1s[b][64+q]);
          const float n = tanh_(gi1s[b][128+q] + r*g1s[b][128+q]);
          h2[b][q] = (1.f-z)*n + z*h2[b][q];
        }
      }
    }
    if (tid >= 512 && tid < 512+BB && (t+1) < TIN)
      *(float4*)&xb[cur^1][tid-512][0] =
        *(const float4*)(x + ((size_t)(bbase+(tid-512))*TIN + (t+1))*NIN);
    __syncthreads();
  }

  // ====== decoder init: switch weights, stage head + dWih0/dbih0 into LDS
  const float4* Wrd = (const float4*)(((m==0)? dWhh0 : (m==1)? dWih1 : dWhh1) + j*HDIM);
  if (m==0){ bh = dbhh0[j]; }
  else if (m==1){ bi = dbih1[j]; }
  else          { bh = dbhh1[j]; }
  if (tid < HDIM)               hw[0][tid] = Won[tid];
  else if (tid < 2*HDIM)        hw[1][tid-HDIM] = Wcv[tid-HDIM];
  else if (tid < 2*HDIM+G3)     dwih0[tid-2*HDIM] = dWih0[tid-2*HDIM];
  else if (tid < 2*HDIM+2*G3)   dbih0s[tid-2*HDIM-G3] = dbih0[tid-2*HDIM-G3];
  if (tid == 560){ hbb[0] = bon[0]; hbb[1] = bcv[0]; }
  __syncthreads();

  // ====== decoder: supersteps; d1 step s (s<TOUT) || d2 step s-1 + heads (s>=1)
  for (int s=0;s<=TOUT;s++){
    if (m==0){
      if (s < TOUT){
        float acc[BB];
        #pragma unroll
        for (int b=0;b<BB;b++) acc[b]=0.f;
        matvec_half<0>(Wrd, h1, acc);
        __builtin_amdgcn_sched_barrier(0);
        matvec_half<1>(Wrd, h1, acc);
        #pragma unroll
        for (int b=0;b<BB;b++) g0s[b][j] = bh + acc[b];
      }
    } else if (m==1){
      if (s >= 1){
        float acc[BB];
        #pragma unroll
        for (int b=0;b<BB;b++) acc[b]=0.f;
        matvec_half<0>(Wrd, h1, acc);
        __builtin_amdgcn_sched_barrier(0);
        matvec_half<1>(Wrd, h1, acc);
        #pragma unroll
        for (int b=0;b<BB;b++) gi1s[b][j] = bi + acc[b];
      }
    } else {
      if (s >= 1){
        float acc[BB];
        #pragma unroll
        for (int b=0;b<BB;b++) acc[b]=0.f;
        matvec_half<0>(Wrd, h2, acc);
        __builtin_amdgcn_sched_barrier(0);
        matvec_half<1>(Wrd, h2, acc);
        #pragma unroll
        for (int b=0;b<BB;b++) g1s[b][j] = bh + acc[b];
      }
    }
    __syncthreads();
    // combine d2[s-1]
    if (s >= 1){
      for (int u=tid; u<BB*HDIM; u+=NTHR){
        const int b=u>>6, q=u&63;
        const float r = sigm(gi1s[b][q]      + g1s[b][q]);
        const float z = sigm(gi1s[b][64+q]   + g1s[b][64+q]);
        const float n = tanh_(gi1s[b][128+q] + r*g1s[b][128+q]);
        h2[b][q] = (1.f-z)*n + z*h2[b][q];
      }
    }
    __syncthreads();
    // heads (s>=1) + combine d1[s] (s<TOUT); cv computed redundantly per lane
    for (int u=tid; u<BB*HDIM; u+=NTHR){
      const int b=u>>6, q=u&63;
      float cv = 0.f;
      if (s >= 1){
        const float4* hv = (const float4*)&h2[b][0];
        const float4* wv = (const float4*)&hw[1][0];
        float a = hbb[1];
        #pragma unroll
        for (int kk=0;kk<16;kk++){ float4 h4 = hv[kk]; float4 w4 = wv[kk];
          a += w4.x*h4.x + w4.y*h4.y + w4.z*h4.z + w4.w*h4.w; }
        cv = a;
        if (q==0) out[(size_t)BATCH*TOUT + (size_t)(bbase+b)*TOUT + (s-1)] = cv;
        if (q==1){
          const float4* wv0 = (const float4*)&hw[0][0];
          float al = hbb[0];
          #pragma unroll
          for (int kk=0;kk<16;kk++){ float4 h4 = hv[kk]; float4 w4 = wv0[kk];
            al += w4.x*h4.x + w4.y*h4.y + w4.z*h4.z + w4.w*h4.w; }
          out[(size_t)(bbase+b)*TOUT + (s-1)] = al;
        }
      }
      if (s < TOUT){
        const float r = sigm((dbih0s[q]      + dwih0[q]*cv)      + g0s[b][q]);
        const float z = sigm((dbih0s[64+q]   + dwih0[64+q]*cv)   + g0s[b][64+q]);
        const float n = tanh_((dbih0s[128+q] + dwih0[128+q]*cv)  + r*g0s[b][128+q]);
        h1[b][q] = (1.f-z)*n + z*h1[b][q];
      }
    }
    __syncthreads();
  }
}

extern "C" void kernel_launch(void* const* d_in, const int* in_sizes, int n_in,
                              void* d_out, int out_size, void* d_ws, size_t ws_size,
                              hipStream_t stream)
{
  const float* x     = (const float*)d_in[0];
  const float* eWih0 = (const float*)d_in[1];
  const float* eWhh0 = (const float*)d_in[2];
  const float* ebih0 = (const float*)d_in[3];
  const float* ebhh0 = (const float*)d_in[4];
  const float* eWih1 = (const float*)d_in[5];
  const float* eWhh1 = (const float*)d_in[6];
  const float* ebih1 = (const float*)d_in[7];
  const float* ebhh1 = (const float*)d_in[8];
  const float* dWih0 = (const float*)d_in[9];
  const float* dWhh0 = (const float*)d_in[10];
  const float* dbih0 = (const float*)d_in[11];
  const float* dbhh0 = (const float*)d_in[12];
  const float* dWih1 = (const float*)d_in[13];
  const float* dWhh1 = (const float*)d_in[14];
  const float* dbih1 = (const float*)d_in[15];
  const float* dbhh1 = (const float*)d_in[16];
  const float* Won   = (const float*)d_in[17];
  const float* bon   = (const float*)d_in[18];
  const float* Wcv   = (const float*)d_in[19];
  const float* bcv   = (const float*)d_in[20];

  gru_seq<<<BATCH/BB, NTHR, 0, stream>>>(
      x, eWih0, eWhh0, ebih0, ebhh0, eWih1, eWhh1, ebih1, ebhh1,
      dWih0, dWhh0, dbih0, dbhh0, dWih1, dWhh1, dbih1, dbhh1,
      Won, bon, Wcv, bcv, (float*)d_out);
}